// Round 11
// baseline (126.222 us; speedup 1.0000x reference)
//
#include <hip/hip_runtime.h>
#include <math.h>

// Capsule dynamic routing, fully fused, 1-BATCH, u_hat SPLIT REG/LDS:
// one block of 512 threads per (b, c). B=256, C=10, N=1152, Din=8, U=16.
//
// Round-11. R10 (merged loads, 2 blocks/CU, 85.5us) runs the W stream at
// ~19 TB/s aggregate L2 = 55% of the 34.5 TB/s ceiling; VALU work is ~5us;
// everything else is latency stalls at 16 waves/CU. The untried lever is
// MORE RESIDENT BLOCKS. Compiler history: at (512,1) it always settles at
// ~128 actual VGPRs -> 2 blocks/CU; any cap below demand spills massively.
// So: SHRINK DEMAND FIRST, then cap.
//  * u_hat groups 0-4 in 5 NAMED float4 regs (20 floats held).
//  * u_hat groups 5-8 in LDS (u_lds, 32 KB): written and re-read by the
//    SAME thread (no cross-thread sharing, no barrier needed); contiguous
//    float4 per wave -> conflict-free.
//  * din-split UHC (R8's proven-clean form): in-flight window 5 float4.
//    Peak demand ~= 20 held + 20 in-flight + ~15 misc = ~55 actual regs.
//  * __launch_bounds__(512, 6): cap floor(512/6)=85, margin ~30 over
//    demand. LDS 38 KB/block <= 53.3 -> 3 blocks/CU = 24 waves = 75%
//    theoretical occupancy (was 50%).
//  * b logits in LDS; x direct from global; iteration 0 peeled
//    (softmax(ones) = 1/1152); c-major grid for W L2 locality.

#define BATCH 256
#define CAPS  10
#define NIN   1152
#define DIN   8
#define UDIM  16
#define TPB   512

__global__ __launch_bounds__(TPB, 6) void capsule_routing_kernel(
    const float* __restrict__ x,   // (B, N, Din)
    const float* __restrict__ W,   // (C, N, Din, U)
    float* __restrict__ out)       // (B, C, U)
{
    const int gblk = blockIdx.x;      // c-major for L2 W-locality
    const int c    = gblk >> 8;       // 0..9
    const int b    = gblk & 255;      // 0..255
    const int t    = threadIdx.x;     // 0..511
    const int uq   = t & 3;           // u quarter: 0..3
    const int ub   = uq << 2;         // u base: 0,4,8,12
    const int gg   = t >> 2;          // 0..127 (n residue)
    const int wave = t >> 6;          // 0..7

    __shared__ float  b_s[NIN];          // routing logits (4.6 KB)
    __shared__ float  redB[8];           // per-wave exp-sum partials
    __shared__ float  ps[8][UDIM];       // per-wave partial s
    __shared__ float  v_s[UDIM];         // squashed output
    __shared__ float4 u_lds[4][128][4];  // u_hat groups 5-8 (32 KB)

    const float* Wc = W + (size_t)c * (NIN * DIN * UDIM);
    const float* xb = x + (size_t)b * (NIN * DIN);

    // u_hat groups 0-4 in 5 NAMED float4 registers (array form spills)
    float4 uh0,uh1,uh2,uh3,uh4;

    // din-split body: computes one group's u_hat fragment into A_
#define UHBODY(K, A_) { \
    const int n_ = gg + 128 * (K); \
    const float4* wr_ = (const float4*)(Wc + n_ * (DIN * UDIM) + ub); \
    { /* din 0..3 */ \
        const float4 xa_ = ((const float4*)(xb + n_ * DIN))[0]; \
        const float4 w0_ = wr_[0], w1_ = wr_[4], w2_ = wr_[8], w3_ = wr_[12]; \
        A_.x = xa_.x*w0_.x + xa_.y*w1_.x + xa_.z*w2_.x + xa_.w*w3_.x; \
        A_.y = xa_.x*w0_.y + xa_.y*w1_.y + xa_.z*w2_.y + xa_.w*w3_.y; \
        A_.z = xa_.x*w0_.z + xa_.y*w1_.z + xa_.z*w2_.z + xa_.w*w3_.z; \
        A_.w = xa_.x*w0_.w + xa_.y*w1_.w + xa_.z*w2_.w + xa_.w*w3_.w; \
    } \
    __builtin_amdgcn_sched_barrier(0); \
    { /* din 4..7 */ \
        const float4 xc_ = ((const float4*)(xb + n_ * DIN))[1]; \
        const float4 w4_ = wr_[16], w5_ = wr_[20], w6_ = wr_[24], w7_ = wr_[28]; \
        A_.x += xc_.x*w4_.x + xc_.y*w5_.x + xc_.z*w6_.x + xc_.w*w7_.x; \
        A_.y += xc_.x*w4_.y + xc_.y*w5_.y + xc_.z*w6_.y + xc_.w*w7_.y; \
        A_.z += xc_.x*w4_.z + xc_.y*w5_.z + xc_.z*w6_.z + xc_.w*w7_.z; \
        A_.w += xc_.x*w4_.w + xc_.y*w5_.w + xc_.z*w6_.w + xc_.w*w7_.w; \
    } } \
    __builtin_amdgcn_sched_barrier(0);

    // groups 0-4 -> registers
    UHBODY(0, uh0)
    UHBODY(1, uh1)
    UHBODY(2, uh2)
    UHBODY(3, uh3)
    UHBODY(4, uh4)
    // groups 5-8 -> LDS (same-thread write/read; no barrier needed)
    {
        float4 a_;
        UHBODY(5, a_)  u_lds[0][gg][uq] = a_;
        UHBODY(6, a_)  u_lds[1][gg][uq] = a_;
        UHBODY(7, a_)  u_lds[2][gg][uq] = a_;
        UHBODY(8, a_)  u_lds[3][gg][uq] = a_;
    }

    float4 p;
    float le;

    // ---- reduction helpers ----
#define PSTAGE(MK) { \
    p.x += __shfl_xor(p.x, MK); p.y += __shfl_xor(p.y, MK); \
    p.z += __shfl_xor(p.z, MK); p.w += __shfl_xor(p.w, MK); }

#define PRED_WRITE() { \
    PSTAGE(4) PSTAGE(8) PSTAGE(16) PSTAGE(32) \
    if ((t & 63) < 4) { \
        ps[wave][ub+0] = p.x; ps[wave][ub+1] = p.y; \
        ps[wave][ub+2] = p.z; ps[wave][ub+3] = p.w; \
    } }

    // squash on first 16 threads
#define SQUASH(USE_RED, WROUT) { \
    __syncthreads(); \
    if (t < UDIM) { \
        float inv_; \
        if (USE_RED) { \
            float es_ = 0.f; \
            es_ += redB[0]; es_ += redB[1]; es_ += redB[2]; es_ += redB[3]; \
            es_ += redB[4]; es_ += redB[5]; es_ += redB[6]; es_ += redB[7]; \
            inv_ = 4.0f / es_;               /* 4x lane overcount in le */ \
        } else { \
            inv_ = 1.0f / 1152.0f;           /* softmax(ones) is uniform */ \
        } \
        float s_ = 0.f; \
        s_ += ps[0][t]; s_ += ps[1][t]; s_ += ps[2][t]; s_ += ps[3][t]; \
        s_ += ps[4][t]; s_ += ps[5][t]; s_ += ps[6][t]; s_ += ps[7][t]; \
        s_ *= inv_; \
        float sq_ = s_ * s_; \
        sq_ += __shfl_xor(sq_, 1); sq_ += __shfl_xor(sq_, 2); \
        sq_ += __shfl_xor(sq_, 4); sq_ += __shfl_xor(sq_, 8); \
        const float sc_ = sq_ / ((1.0f + sq_) * sqrtf(sq_ + 1e-9f)); \
        const float v_ = sc_ * s_; \
        v_s[t] = v_; \
        if (WROUT) out[((size_t)b * CAPS + c) * UDIM + t] = v_; \
    } \
    __syncthreads(); }

    // b update from a register-held group
#define BUP(K, UH, INIT) { \
    float q_ = UH.x*v4_.x + UH.y*v4_.y + UH.z*v4_.z + UH.w*v4_.w; \
    q_ += __shfl_xor(q_, 1); q_ += __shfl_xor(q_, 2); \
    if ((t & 3) == 0) { \
        const int n_ = gg + 128 * (K); \
        if (INIT) b_s[n_] = 1.0f + q_; \
        else      b_s[n_] += q_; \
    } }

    // b update from an LDS-held group
#define BUPL(K, KL, INIT) { \
    const float4 u_ = u_lds[KL][gg][uq]; \
    float q_ = u_.x*v4_.x + u_.y*v4_.y + u_.z*v4_.z + u_.w*v4_.w; \
    q_ += __shfl_xor(q_, 1); q_ += __shfl_xor(q_, 2); \
    if ((t & 3) == 0) { \
        const int n_ = gg + 128 * (K); \
        if (INIT) b_s[n_] = 1.0f + q_; \
        else      b_s[n_] += q_; \
    } }

#define BUPD_ALL(INIT) { \
    const float4 v4_ = *(const float4*)(v_s + ub); \
    BUP(0, uh0, INIT) BUP(1, uh1, INIT) BUP(2, uh2, INIT) \
    BUP(3, uh3, INIT) BUP(4, uh4, INIT) \
    BUPL(5, 0, INIT) BUPL(6, 1, INIT) \
    BUPL(7, 2, INIT) BUPL(8, 3, INIT) \
    __syncthreads(); }

#define PADD(UH) { \
    p.x += UH.x; p.y += UH.y; p.z += UH.z; p.w += UH.w; }

#define PADDL(KL) { \
    const float4 u_ = u_lds[KL][gg][uq]; \
    p.x += u_.x; p.y += u_.y; p.z += u_.z; p.w += u_.w; }

#define ACCE(K, UH) { \
    const float e_ = expf(b_s[gg + 128*(K)]); \
    le += e_; \
    p.x += e_*UH.x; p.y += e_*UH.y; p.z += e_*UH.z; p.w += e_*UH.w; }

#define ACCEL(K, KL) { \
    const float e_ = expf(b_s[gg + 128*(K)]); \
    le += e_; \
    const float4 u_ = u_lds[KL][gg][uq]; \
    p.x += e_*u_.x; p.y += e_*u_.y; p.z += e_*u_.z; p.w += e_*u_.w; }

#define LERED_WRITE() { \
    le += __shfl_xor(le, 1);  le += __shfl_xor(le, 2); \
    le += __shfl_xor(le, 4);  le += __shfl_xor(le, 8); \
    le += __shfl_xor(le, 16); le += __shfl_xor(le, 32); \
    if ((t & 63) == 0) redB[wave] = le; }

    // ---- iteration 0: c is uniform 1/1152, no exp needed ----
    p = uh0;
    PADD(uh1) PADD(uh2) PADD(uh3) PADD(uh4)
    PADDL(0) PADDL(1) PADDL(2) PADDL(3)
    PRED_WRITE()
    SQUASH(0, 0)
    BUPD_ALL(1)            // b = 1 + u_hat . v0

    // ---- iteration 1 ----
    le = 0.f;
    p = make_float4(0.f, 0.f, 0.f, 0.f);
    ACCE(0, uh0) ACCE(1, uh1) ACCE(2, uh2)
    ACCE(3, uh3) ACCE(4, uh4)
    ACCEL(5, 0) ACCEL(6, 1) ACCEL(7, 2) ACCEL(8, 3)
    LERED_WRITE()
    PRED_WRITE()
    SQUASH(1, 0)
    BUPD_ALL(0)            // b += u_hat . v1

    // ---- iteration 2 (writes out) ----
    le = 0.f;
    p = make_float4(0.f, 0.f, 0.f, 0.f);
    ACCE(0, uh0) ACCE(1, uh1) ACCE(2, uh2)
    ACCE(3, uh3) ACCE(4, uh4)
    ACCEL(5, 0) ACCEL(6, 1) ACCEL(7, 2) ACCEL(8, 3)
    LERED_WRITE()
    PRED_WRITE()
    SQUASH(1, 1)
}

extern "C" void kernel_launch(void* const* d_in, const int* in_sizes, int n_in,
                              void* d_out, int out_size, void* d_ws, size_t ws_size,
                              hipStream_t stream) {
    const float* x = (const float*)d_in[0];   // (256, 1152, 8)
    const float* W = (const float*)d_in[1];   // (10, 1152, 8, 16)
    float* out = (float*)d_out;               // (256, 10, 16)
    capsule_routing_kernel<<<BATCH * CAPS, TPB, 0, stream>>>(x, W, out);
}

// Round 12
// 116.051 us; speedup vs baseline: 1.0876x; 1.0876x over previous
//
#include <hip/hip_runtime.h>
#include <math.h>

// Capsule dynamic routing, fully fused, 2-BATCH + u_hat SPLIT REG/LDS:
// one block of 512 threads per (c, batch-pair). B=256, C=10, N=1152,
// Din=8, U=16, 3 routing iterations.
//
// Round-12. Evidence: R0/R10/R11 (1-batch, occ 42/40/60%, MLP 5/10/5) all
// converge at 1.5 GB / ~82-90us = ~18 TB/s aggregate L2 -- an L2-streaming
// ceiling for this pattern (34.5 TB/s ubench includes L1 reuse; W stream
// has none). Latency levers are exhausted (+4-5% each). Remaining lever:
// TRAFFIC. 2-batch halves W traffic (0.85 GB) -> ~45-55us at the same
// delivery rate. R6's 2-batch failed only because 200 regs -> 1 block/CU
// (occ 22%); fix with R11's proven same-thread LDS offload:
//  * u_hat groups 0-5 in 12 NAMED float4 regs (48 floats held).
//  * u_hat groups 6-8 x 2 batches in LDS (48 KB), same-thread write/read,
//    no barrier needed, conflict-free float4 pattern (R11-proven).
//  * din-split UHC (R6's exact form): in-flight window 6 float4 = 24 regs.
//    Demand ~= 48 + 24 + ~20 = ~92 actual.
//  * __launch_bounds__(512, 2): cap 128 actual (margin ~35); prevents the
//    compiler drifting to the 200-reg/1-block tier (R6's failure). LDS
//    58.5 KB/block also pins 2 blocks/CU = 16 waves (R10's wave count,
//    which sustained 18 TB/s).
//  * b logits in LDS; x direct from global; iteration 0 peeled
//    (softmax(ones) = 1/1152); c-major grid for W L2 locality.

#define BATCH 256
#define CAPS  10
#define NIN   1152
#define DIN   8
#define UDIM  16
#define TPB   512

__global__ __launch_bounds__(TPB, 2) void capsule_routing_kernel(
    const float* __restrict__ x,   // (B, N, Din)
    const float* __restrict__ W,   // (C, N, Din, U)
    float* __restrict__ out)       // (B, C, U)
{
    const int gblk = blockIdx.x;      // c-major for L2 W-locality
    const int c    = gblk >> 7;       // 0..9
    const int bp   = gblk & 127;      // 0..127  (batch pair)
    const int b0   = bp << 1;
    const int t    = threadIdx.x;     // 0..511
    const int uq   = t & 3;           // u quarter: 0..3
    const int ub   = uq << 2;         // u base: 0,4,8,12
    const int gg   = t >> 2;          // 0..127 (n residue)
    const int wave = t >> 6;          // 0..7

    __shared__ float  b_s[2][NIN];        // routing logits (9.2 KB)
    __shared__ float  redB[2][8];         // per-wave exp-sum partials
    __shared__ float  ps[2][8][UDIM];     // per-wave partial s
    __shared__ float  v_s[2][UDIM];       // squashed output
    __shared__ float4 u_lds[2][3][128][4]; // u_hat groups 6-8 (48 KB)

    const float* Wc = W + (size_t)c * (NIN * DIN * UDIM);
    const float* xA = x + (size_t)b0 * (NIN * DIN);
    const float* xB = xA + (NIN * DIN);

    // u_hat groups 0-5 in 12 NAMED float4 registers (array form spills)
    float4 uA0,uA1,uA2,uA3,uA4,uA5;
    float4 uB0,uB1,uB2,uB3,uB4,uB5;

    // din-split 2-batch body (R6's proven form): computes one group's
    // u_hat fragments for both batches into A_, D_.
#define UHBODY(K, A_, D_) { \
    const int n_ = gg + 128 * (K); \
    const float4* wr_ = (const float4*)(Wc + n_ * (DIN * UDIM) + ub); \
    { /* din 0..3 */ \
        const float4 xa_ = ((const float4*)(xA + n_ * DIN))[0]; \
        const float4 ya_ = ((const float4*)(xB + n_ * DIN))[0]; \
        const float4 w0_ = wr_[0], w1_ = wr_[4], w2_ = wr_[8], w3_ = wr_[12]; \
        A_.x = xa_.x*w0_.x + xa_.y*w1_.x + xa_.z*w2_.x + xa_.w*w3_.x; \
        A_.y = xa_.x*w0_.y + xa_.y*w1_.y + xa_.z*w2_.y + xa_.w*w3_.y; \
        A_.z = xa_.x*w0_.z + xa_.y*w1_.z + xa_.z*w2_.z + xa_.w*w3_.z; \
        A_.w = xa_.x*w0_.w + xa_.y*w1_.w + xa_.z*w2_.w + xa_.w*w3_.w; \
        D_.x = ya_.x*w0_.x + ya_.y*w1_.x + ya_.z*w2_.x + ya_.w*w3_.x; \
        D_.y = ya_.x*w0_.y + ya_.y*w1_.y + ya_.z*w2_.y + ya_.w*w3_.y; \
        D_.z = ya_.x*w0_.z + ya_.y*w1_.z + ya_.z*w2_.z + ya_.w*w3_.z; \
        D_.w = ya_.x*w0_.w + ya_.y*w1_.w + ya_.z*w2_.w + ya_.w*w3_.w; \
    } \
    __builtin_amdgcn_sched_barrier(0); \
    { /* din 4..7 */ \
        const float4 xb_ = ((const float4*)(xA + n_ * DIN))[1]; \
        const float4 yb_ = ((const float4*)(xB + n_ * DIN))[1]; \
        const float4 w4_ = wr_[16], w5_ = wr_[20], w6_ = wr_[24], w7_ = wr_[28]; \
        A_.x += xb_.x*w4_.x + xb_.y*w5_.x + xb_.z*w6_.x + xb_.w*w7_.x; \
        A_.y += xb_.x*w4_.y + xb_.y*w5_.y + xb_.z*w6_.y + xb_.w*w7_.y; \
        A_.z += xb_.x*w4_.z + xb_.y*w5_.z + xb_.z*w6_.z + xb_.w*w7_.z; \
        A_.w += xb_.x*w4_.w + xb_.y*w5_.w + xb_.z*w6_.w + xb_.w*w7_.w; \
        D_.x += yb_.x*w4_.x + yb_.y*w5_.x + yb_.z*w6_.x + yb_.w*w7_.x; \
        D_.y += yb_.x*w4_.y + yb_.y*w5_.y + yb_.z*w6_.y + yb_.w*w7_.y; \
        D_.z += yb_.x*w4_.z + yb_.y*w5_.z + yb_.z*w6_.z + yb_.w*w7_.z; \
        D_.w += yb_.x*w4_.w + yb_.y*w5_.w + yb_.z*w6_.w + yb_.w*w7_.w; \
    } } \
    __builtin_amdgcn_sched_barrier(0);

    // groups 0-5 -> registers
    UHBODY(0, uA0, uB0)
    UHBODY(1, uA1, uB1)
    UHBODY(2, uA2, uB2)
    UHBODY(3, uA3, uB3)
    UHBODY(4, uA4, uB4)
    UHBODY(5, uA5, uB5)
    // groups 6-8 -> LDS (same-thread write/read; no barrier needed)
    {
        float4 a_, d_;
        UHBODY(6, a_, d_)  u_lds[0][0][gg][uq] = a_; u_lds[1][0][gg][uq] = d_;
        UHBODY(7, a_, d_)  u_lds[0][1][gg][uq] = a_; u_lds[1][1][gg][uq] = d_;
        UHBODY(8, a_, d_)  u_lds[0][2][gg][uq] = a_; u_lds[1][2][gg][uq] = d_;
    }

    float4 pA, pB;
    float leA, leB;

    // ---- reduction helpers ----
#define PSTAGE(MK) { \
    pA.x += __shfl_xor(pA.x, MK); pA.y += __shfl_xor(pA.y, MK); \
    pA.z += __shfl_xor(pA.z, MK); pA.w += __shfl_xor(pA.w, MK); \
    pB.x += __shfl_xor(pB.x, MK); pB.y += __shfl_xor(pB.y, MK); \
    pB.z += __shfl_xor(pB.z, MK); pB.w += __shfl_xor(pB.w, MK); }

#define PRED_WRITE() { \
    PSTAGE(4) PSTAGE(8) PSTAGE(16) PSTAGE(32) \
    if ((t & 63) < 4) { \
        ps[0][wave][ub+0] = pA.x; ps[0][wave][ub+1] = pA.y; \
        ps[0][wave][ub+2] = pA.z; ps[0][wave][ub+3] = pA.w; \
        ps[1][wave][ub+0] = pB.x; ps[1][wave][ub+1] = pB.y; \
        ps[1][wave][ub+2] = pB.z; ps[1][wave][ub+3] = pB.w; \
    } }

    // squash: threads 0..31 (wave 0). bi = batch, u = component.
#define SQUASH(USE_RED, WROUT) { \
    __syncthreads(); \
    if (t < 32) { \
        const int bi_ = t >> 4, u_ = t & 15; \
        float inv_; \
        if (USE_RED) { \
            float es_ = 0.f; \
            es_ += redB[bi_][0]; es_ += redB[bi_][1]; es_ += redB[bi_][2]; es_ += redB[bi_][3]; \
            es_ += redB[bi_][4]; es_ += redB[bi_][5]; es_ += redB[bi_][6]; es_ += redB[bi_][7]; \
            inv_ = 4.0f / es_;               /* 4x lane overcount in le */ \
        } else { \
            inv_ = 1.0f / 1152.0f;           /* softmax(ones) is uniform */ \
        } \
        float s_ = 0.f; \
        s_ += ps[bi_][0][u_]; s_ += ps[bi_][1][u_]; s_ += ps[bi_][2][u_]; s_ += ps[bi_][3][u_]; \
        s_ += ps[bi_][4][u_]; s_ += ps[bi_][5][u_]; s_ += ps[bi_][6][u_]; s_ += ps[bi_][7][u_]; \
        s_ *= inv_; \
        float sq_ = s_ * s_; \
        sq_ += __shfl_xor(sq_, 1); sq_ += __shfl_xor(sq_, 2); \
        sq_ += __shfl_xor(sq_, 4); sq_ += __shfl_xor(sq_, 8); \
        const float sc_ = sq_ / ((1.0f + sq_) * sqrtf(sq_ + 1e-9f)); \
        const float v_ = sc_ * s_; \
        v_s[bi_][u_] = v_; \
        if (WROUT) out[((size_t)(b0 + bi_) * CAPS + c) * UDIM + u_] = v_; \
    } \
    __syncthreads(); }

    // b update from register-held groups
#define BUP(K, UA, UB, INIT) { \
    float qa_ = UA.x*vA_.x + UA.y*vA_.y + UA.z*vA_.z + UA.w*vA_.w; \
    float qb_ = UB.x*vB_.x + UB.y*vB_.y + UB.z*vB_.z + UB.w*vB_.w; \
    qa_ += __shfl_xor(qa_, 1); qa_ += __shfl_xor(qa_, 2); \
    qb_ += __shfl_xor(qb_, 1); qb_ += __shfl_xor(qb_, 2); \
    if ((t & 3) == 0) { \
        const int n_ = gg + 128 * (K); \
        if (INIT) { b_s[0][n_] = 1.0f + qa_; b_s[1][n_] = 1.0f + qb_; } \
        else      { b_s[0][n_] += qa_;       b_s[1][n_] += qb_; } \
    } }

    // b update from LDS-held groups
#define BUPL(K, KL, INIT) { \
    const float4 uA_ = u_lds[0][KL][gg][uq]; \
    const float4 uB_ = u_lds[1][KL][gg][uq]; \
    float qa_ = uA_.x*vA_.x + uA_.y*vA_.y + uA_.z*vA_.z + uA_.w*vA_.w; \
    float qb_ = uB_.x*vB_.x + uB_.y*vB_.y + uB_.z*vB_.z + uB_.w*vB_.w; \
    qa_ += __shfl_xor(qa_, 1); qa_ += __shfl_xor(qa_, 2); \
    qb_ += __shfl_xor(qb_, 1); qb_ += __shfl_xor(qb_, 2); \
    if ((t & 3) == 0) { \
        const int n_ = gg + 128 * (K); \
        if (INIT) { b_s[0][n_] = 1.0f + qa_; b_s[1][n_] = 1.0f + qb_; } \
        else      { b_s[0][n_] += qa_;       b_s[1][n_] += qb_; } \
    } }

#define BUPD_ALL(INIT) { \
    const float4 vA_ = *(const float4*)(&v_s[0][ub]); \
    const float4 vB_ = *(const float4*)(&v_s[1][ub]); \
    BUP(0, uA0, uB0, INIT) BUP(1, uA1, uB1, INIT) \
    BUP(2, uA2, uB2, INIT) BUP(3, uA3, uB3, INIT) \
    BUP(4, uA4, uB4, INIT) BUP(5, uA5, uB5, INIT) \
    BUPL(6, 0, INIT) BUPL(7, 1, INIT) BUPL(8, 2, INIT) \
    __syncthreads(); }

#define PADD(UA, UB) { \
    pA.x += UA.x; pA.y += UA.y; pA.z += UA.z; pA.w += UA.w; \
    pB.x += UB.x; pB.y += UB.y; pB.z += UB.z; pB.w += UB.w; }

#define PADDL(KL) { \
    const float4 uA_ = u_lds[0][KL][gg][uq]; \
    const float4 uB_ = u_lds[1][KL][gg][uq]; \
    pA.x += uA_.x; pA.y += uA_.y; pA.z += uA_.z; pA.w += uA_.w; \
    pB.x += uB_.x; pB.y += uB_.y; pB.z += uB_.z; pB.w += uB_.w; }

#define ACCE(K, UA, UB) { \
    const float eA_ = expf(b_s[0][gg + 128*(K)]); \
    const float eB_ = expf(b_s[1][gg + 128*(K)]); \
    leA += eA_; leB += eB_; \
    pA.x += eA_*UA.x; pA.y += eA_*UA.y; pA.z += eA_*UA.z; pA.w += eA_*UA.w; \
    pB.x += eB_*UB.x; pB.y += eB_*UB.y; pB.z += eB_*UB.z; pB.w += eB_*UB.w; }

#define ACCEL(K, KL) { \
    const float eA_ = expf(b_s[0][gg + 128*(K)]); \
    const float eB_ = expf(b_s[1][gg + 128*(K)]); \
    leA += eA_; leB += eB_; \
    const float4 uA_ = u_lds[0][KL][gg][uq]; \
    const float4 uB_ = u_lds[1][KL][gg][uq]; \
    pA.x += eA_*uA_.x; pA.y += eA_*uA_.y; pA.z += eA_*uA_.z; pA.w += eA_*uA_.w; \
    pB.x += eB_*uB_.x; pB.y += eB_*uB_.y; pB.z += eB_*uB_.z; pB.w += eB_*uB_.w; }

#define LERED_WRITE() { \
    leA += __shfl_xor(leA, 1);  leB += __shfl_xor(leB, 1); \
    leA += __shfl_xor(leA, 2);  leB += __shfl_xor(leB, 2); \
    leA += __shfl_xor(leA, 4);  leB += __shfl_xor(leB, 4); \
    leA += __shfl_xor(leA, 8);  leB += __shfl_xor(leB, 8); \
    leA += __shfl_xor(leA, 16); leB += __shfl_xor(leB, 16); \
    leA += __shfl_xor(leA, 32); leB += __shfl_xor(leB, 32); \
    if ((t & 63) == 0) { redB[0][wave] = leA; redB[1][wave] = leB; } }

    // ---- iteration 0: c is uniform 1/1152, no exp needed ----
    pA = uA0; pB = uB0;
    PADD(uA1, uB1) PADD(uA2, uB2) PADD(uA3, uB3)
    PADD(uA4, uB4) PADD(uA5, uB5)
    PADDL(0) PADDL(1) PADDL(2)
    PRED_WRITE()
    SQUASH(0, 0)
    BUPD_ALL(1)            // b = 1 + u_hat . v0

    // ---- iteration 1 ----
    leA = 0.f; leB = 0.f;
    pA = make_float4(0.f, 0.f, 0.f, 0.f); pB = make_float4(0.f, 0.f, 0.f, 0.f);
    ACCE(0, uA0, uB0) ACCE(1, uA1, uB1) ACCE(2, uA2, uB2)
    ACCE(3, uA3, uB3) ACCE(4, uA4, uB4) ACCE(5, uA5, uB5)
    ACCEL(6, 0) ACCEL(7, 1) ACCEL(8, 2)
    LERED_WRITE()
    PRED_WRITE()
    SQUASH(1, 0)
    BUPD_ALL(0)            // b += u_hat . v1

    // ---- iteration 2 (writes out) ----
    leA = 0.f; leB = 0.f;
    pA = make_float4(0.f, 0.f, 0.f, 0.f); pB = make_float4(0.f, 0.f, 0.f, 0.f);
    ACCE(0, uA0, uB0) ACCE(1, uA1, uB1) ACCE(2, uA2, uB2)
    ACCE(3, uA3, uB3) ACCE(4, uA4, uB4) ACCE(5, uA5, uB5)
    ACCEL(6, 0) ACCEL(7, 1) ACCEL(8, 2)
    LERED_WRITE()
    PRED_WRITE()
    SQUASH(1, 1)
}

extern "C" void kernel_launch(void* const* d_in, const int* in_sizes, int n_in,
                              void* d_out, int out_size, void* d_ws, size_t ws_size,
                              hipStream_t stream) {
    const float* x = (const float*)d_in[0];   // (256, 1152, 8)
    const float* W = (const float*)d_in[1];   // (10, 1152, 8, 16)
    float* out = (float*)d_out;               // (256, 10, 16)
    capsule_routing_kernel<<<CAPS * (BATCH / 2), TPB, 0, stream>>>(x, W, out);
}

// Round 15
// 112.757 us; speedup vs baseline: 1.1194x; 1.0292x over previous
//
#include <hip/hip_runtime.h>
#include <math.h>

// Capsule dynamic routing, fully fused, 2-BATCH + u_hat SPLIT REG/LDS:
// one block of 512 threads per (c, batch-pair). B=256, C=10, N=1152,
// Din=8, U=16, 3 routing iterations.
//
// Round-15 = round-13 resubmitted a third time (rounds 13 and 14 both died
// in container acquisition -- broker outage window; kernel content cannot
// hang: diff vs clean-running R12 is exp2f, -4 shuffles, -1 dead barrier).
// R12 baseline: 74.5us rocprof, clean (no spill, 120 actual regs, 2
// blocks/CU, occ 38%). R12 post-mortem: traffic halving gave only +10%
// because the 3 routing iterations (18 expf + ~150 FMA + ~80 shfl + 3
// barriers per wave each) are co-equal with the W stream.
// Changes vs R12 (all arithmetic-safe, no structure/regalloc change):
//  * expf -> exp2f(b * log2(e)): ~10 instr -> ~2 (v_exp_f32 is native).
//    Softmax num/denom share e -> error cancels; b in [0.3,3], rel ~1e-7.
//  * LERED 6->4 stages: masks 1,2 only summed the 4 identical uq-copies
//    (the 4x overcount). Skip them; inv = 1/esum exactly.
//  * Final SQUASH's trailing barrier removed (nothing follows it).
// Structure kept from R12: u_hat groups 0-5 in 12 NAMED float4 regs,
// groups 6-8 in LDS (48 KB, same-thread write/read); din-split UHC
// (in-flight 6 float4 -- merged form risks >128 regs = spill); b logits
// in LDS; x direct from global; iter 0 peeled; launch_bounds(512,2).

#define BATCH 256
#define CAPS  10
#define NIN   1152
#define DIN   8
#define UDIM  16
#define TPB   512
#define LOG2E 1.4426950408889634f

__global__ __launch_bounds__(TPB, 2) void capsule_routing_kernel(
    const float* __restrict__ x,   // (B, N, Din)
    const float* __restrict__ W,   // (C, N, Din, U)
    float* __restrict__ out)       // (B, C, U)
{
    const int gblk = blockIdx.x;      // c-major for L2 W-locality
    const int c    = gblk >> 7;       // 0..9
    const int bp   = gblk & 127;      // 0..127  (batch pair)
    const int b0   = bp << 1;
    const int t    = threadIdx.x;     // 0..511
    const int uq   = t & 3;           // u quarter: 0..3
    const int ub   = uq << 2;         // u base: 0,4,8,12
    const int gg   = t >> 2;          // 0..127 (n residue)
    const int wave = t >> 6;          // 0..7

    __shared__ float  b_s[2][NIN];        // routing logits (9.2 KB)
    __shared__ float  redB[2][8];         // per-wave exp-sum partials
    __shared__ float  ps[2][8][UDIM];     // per-wave partial s
    __shared__ float  v_s[2][UDIM];       // squashed output
    __shared__ float4 u_lds[2][3][128][4]; // u_hat groups 6-8 (48 KB)

    const float* Wc = W + (size_t)c * (NIN * DIN * UDIM);
    const float* xA = x + (size_t)b0 * (NIN * DIN);
    const float* xB = xA + (NIN * DIN);

    // u_hat groups 0-5 in 12 NAMED float4 registers (array form spills)
    float4 uA0,uA1,uA2,uA3,uA4,uA5;
    float4 uB0,uB1,uB2,uB3,uB4,uB5;

    // din-split 2-batch body (R6/R12's proven form)
#define UHBODY(K, A_, D_) { \
    const int n_ = gg + 128 * (K); \
    const float4* wr_ = (const float4*)(Wc + n_ * (DIN * UDIM) + ub); \
    { /* din 0..3 */ \
        const float4 xa_ = ((const float4*)(xA + n_ * DIN))[0]; \
        const float4 ya_ = ((const float4*)(xB + n_ * DIN))[0]; \
        const float4 w0_ = wr_[0], w1_ = wr_[4], w2_ = wr_[8], w3_ = wr_[12]; \
        A_.x = xa_.x*w0_.x + xa_.y*w1_.x + xa_.z*w2_.x + xa_.w*w3_.x; \
        A_.y = xa_.x*w0_.y + xa_.y*w1_.y + xa_.z*w2_.y + xa_.w*w3_.y; \
        A_.z = xa_.x*w0_.z + xa_.y*w1_.z + xa_.z*w2_.z + xa_.w*w3_.z; \
        A_.w = xa_.x*w0_.w + xa_.y*w1_.w + xa_.z*w2_.w + xa_.w*w3_.w; \
        D_.x = ya_.x*w0_.x + ya_.y*w1_.x + ya_.z*w2_.x + ya_.w*w3_.x; \
        D_.y = ya_.x*w0_.y + ya_.y*w1_.y + ya_.z*w2_.y + ya_.w*w3_.y; \
        D_.z = ya_.x*w0_.z + ya_.y*w1_.z + ya_.z*w2_.z + ya_.w*w3_.z; \
        D_.w = ya_.x*w0_.w + ya_.y*w1_.w + ya_.z*w2_.w + ya_.w*w3_.w; \
    } \
    __builtin_amdgcn_sched_barrier(0); \
    { /* din 4..7 */ \
        const float4 xb_ = ((const float4*)(xA + n_ * DIN))[1]; \
        const float4 yb_ = ((const float4*)(xB + n_ * DIN))[1]; \
        const float4 w4_ = wr_[16], w5_ = wr_[20], w6_ = wr_[24], w7_ = wr_[28]; \
        A_.x += xb_.x*w4_.x + xb_.y*w5_.x + xb_.z*w6_.x + xb_.w*w7_.x; \
        A_.y += xb_.x*w4_.y + xb_.y*w5_.y + xb_.z*w6_.y + xb_.w*w7_.y; \
        A_.z += xb_.x*w4_.z + xb_.y*w5_.z + xb_.z*w6_.z + xb_.w*w7_.z; \
        A_.w += xb_.x*w4_.w + xb_.y*w5_.w + xb_.z*w6_.w + xb_.w*w7_.w; \
        D_.x += yb_.x*w4_.x + yb_.y*w5_.x + yb_.z*w6_.x + yb_.w*w7_.x; \
        D_.y += yb_.x*w4_.y + yb_.y*w5_.y + yb_.z*w6_.y + yb_.w*w7_.y; \
        D_.z += yb_.x*w4_.z + yb_.y*w5_.z + yb_.z*w6_.z + yb_.w*w7_.z; \
        D_.w += yb_.x*w4_.w + yb_.y*w5_.w + yb_.z*w6_.w + yb_.w*w7_.w; \
    } } \
    __builtin_amdgcn_sched_barrier(0);

    // groups 0-5 -> registers
    UHBODY(0, uA0, uB0)
    UHBODY(1, uA1, uB1)
    UHBODY(2, uA2, uB2)
    UHBODY(3, uA3, uB3)
    UHBODY(4, uA4, uB4)
    UHBODY(5, uA5, uB5)
    // groups 6-8 -> LDS (same-thread write/read; no barrier needed)
    {
        float4 a_, d_;
        UHBODY(6, a_, d_)  u_lds[0][0][gg][uq] = a_; u_lds[1][0][gg][uq] = d_;
        UHBODY(7, a_, d_)  u_lds[0][1][gg][uq] = a_; u_lds[1][1][gg][uq] = d_;
        UHBODY(8, a_, d_)  u_lds[0][2][gg][uq] = a_; u_lds[1][2][gg][uq] = d_;
    }

    float4 pA, pB;
    float leA, leB;

    // ---- reduction helpers ----
#define PSTAGE(MK) { \
    pA.x += __shfl_xor(pA.x, MK); pA.y += __shfl_xor(pA.y, MK); \
    pA.z += __shfl_xor(pA.z, MK); pA.w += __shfl_xor(pA.w, MK); \
    pB.x += __shfl_xor(pB.x, MK); pB.y += __shfl_xor(pB.y, MK); \
    pB.z += __shfl_xor(pB.z, MK); pB.w += __shfl_xor(pB.w, MK); }

#define PRED_WRITE() { \
    PSTAGE(4) PSTAGE(8) PSTAGE(16) PSTAGE(32) \
    if ((t & 63) < 4) { \
        ps[0][wave][ub+0] = pA.x; ps[0][wave][ub+1] = pA.y; \
        ps[0][wave][ub+2] = pA.z; ps[0][wave][ub+3] = pA.w; \
        ps[1][wave][ub+0] = pB.x; ps[1][wave][ub+1] = pB.y; \
        ps[1][wave][ub+2] = pB.z; ps[1][wave][ub+3] = pB.w; \
    } }

    // squash: threads 0..31 (wave 0). bi = batch, u = component.
    // LASTB: emit the trailing barrier (skip on the final iteration).
#define SQUASH(USE_RED, WROUT, LASTB) { \
    __syncthreads(); \
    if (t < 32) { \
        const int bi_ = t >> 4, u_ = t & 15; \
        float inv_; \
        if (USE_RED) { \
            float es_ = 0.f; \
            es_ += redB[bi_][0]; es_ += redB[bi_][1]; es_ += redB[bi_][2]; es_ += redB[bi_][3]; \
            es_ += redB[bi_][4]; es_ += redB[bi_][5]; es_ += redB[bi_][6]; es_ += redB[bi_][7]; \
            inv_ = 1.0f / es_;               /* le counted once (4-stage) */ \
        } else { \
            inv_ = 1.0f / 1152.0f;           /* softmax(ones) is uniform */ \
        } \
        float s_ = 0.f; \
        s_ += ps[bi_][0][u_]; s_ += ps[bi_][1][u_]; s_ += ps[bi_][2][u_]; s_ += ps[bi_][3][u_]; \
        s_ += ps[bi_][4][u_]; s_ += ps[bi_][5][u_]; s_ += ps[bi_][6][u_]; s_ += ps[bi_][7][u_]; \
        s_ *= inv_; \
        float sq_ = s_ * s_; \
        sq_ += __shfl_xor(sq_, 1); sq_ += __shfl_xor(sq_, 2); \
        sq_ += __shfl_xor(sq_, 4); sq_ += __shfl_xor(sq_, 8); \
        const float sc_ = sq_ / ((1.0f + sq_) * sqrtf(sq_ + 1e-9f)); \
        const float v_ = sc_ * s_; \
        v_s[bi_][u_] = v_; \
        if (WROUT) out[((size_t)(b0 + bi_) * CAPS + c) * UDIM + u_] = v_; \
    } \
    if (LASTB) __syncthreads(); }

    // b update from register-held groups
#define BUP(K, UA, UB, INIT) { \
    float qa_ = UA.x*vA_.x + UA.y*vA_.y + UA.z*vA_.z + UA.w*vA_.w; \
    float qb_ = UB.x*vB_.x + UB.y*vB_.y + UB.z*vB_.z + UB.w*vB_.w; \
    qa_ += __shfl_xor(qa_, 1); qa_ += __shfl_xor(qa_, 2); \
    qb_ += __shfl_xor(qb_, 1); qb_ += __shfl_xor(qb_, 2); \
    if ((t & 3) == 0) { \
        const int n_ = gg + 128 * (K); \
        if (INIT) { b_s[0][n_] = 1.0f + qa_; b_s[1][n_] = 1.0f + qb_; } \
        else      { b_s[0][n_] += qa_;       b_s[1][n_] += qb_; } \
    } }

    // b update from LDS-held groups
#define BUPL(K, KL, INIT) { \
    const float4 uA_ = u_lds[0][KL][gg][uq]; \
    const float4 uB_ = u_lds[1][KL][gg][uq]; \
    float qa_ = uA_.x*vA_.x + uA_.y*vA_.y + uA_.z*vA_.z + uA_.w*vA_.w; \
    float qb_ = uB_.x*vB_.x + uB_.y*vB_.y + uB_.z*vB_.z + uB_.w*vB_.w; \
    qa_ += __shfl_xor(qa_, 1); qa_ += __shfl_xor(qa_, 2); \
    qb_ += __shfl_xor(qb_, 1); qb_ += __shfl_xor(qb_, 2); \
    if ((t & 3) == 0) { \
        const int n_ = gg + 128 * (K); \
        if (INIT) { b_s[0][n_] = 1.0f + qa_; b_s[1][n_] = 1.0f + qb_; } \
        else      { b_s[0][n_] += qa_;       b_s[1][n_] += qb_; } \
    } }

#define BUPD_ALL(INIT) { \
    const float4 vA_ = *(const float4*)(&v_s[0][ub]); \
    const float4 vB_ = *(const float4*)(&v_s[1][ub]); \
    BUP(0, uA0, uB0, INIT) BUP(1, uA1, uB1, INIT) \
    BUP(2, uA2, uB2, INIT) BUP(3, uA3, uB3, INIT) \
    BUP(4, uA4, uB4, INIT) BUP(5, uA5, uB5, INIT) \
    BUPL(6, 0, INIT) BUPL(7, 1, INIT) BUPL(8, 2, INIT) \
    __syncthreads(); }

#define PADD(UA, UB) { \
    pA.x += UA.x; pA.y += UA.y; pA.z += UA.z; pA.w += UA.w; \
    pB.x += UB.x; pB.y += UB.y; pB.z += UB.z; pB.w += UB.w; }

#define PADDL(KL) { \
    const float4 uA_ = u_lds[0][KL][gg][uq]; \
    const float4 uB_ = u_lds[1][KL][gg][uq]; \
    pA.x += uA_.x; pA.y += uA_.y; pA.z += uA_.z; pA.w += uA_.w; \
    pB.x += uB_.x; pB.y += uB_.y; pB.z += uB_.z; pB.w += uB_.w; }

    // fast exp: exp(b) = exp2(b * log2 e) -> v_mul + v_exp_f32 (~1 ulp).
#define ACCE(K, UA, UB) { \
    const float eA_ = exp2f(b_s[0][gg + 128*(K)] * LOG2E); \
    const float eB_ = exp2f(b_s[1][gg + 128*(K)] * LOG2E); \
    leA += eA_; leB += eB_; \
    pA.x += eA_*UA.x; pA.y += eA_*UA.y; pA.z += eA_*UA.z; pA.w += eA_*UA.w; \
    pB.x += eB_*UB.x; pB.y += eB_*UB.y; pB.z += eB_*UB.z; pB.w += eB_*UB.w; }

#define ACCEL(K, KL) { \
    const float eA_ = exp2f(b_s[0][gg + 128*(K)] * LOG2E); \
    const float eB_ = exp2f(b_s[1][gg + 128*(K)] * LOG2E); \
    leA += eA_; leB += eB_; \
    const float4 uA_ = u_lds[0][KL][gg][uq]; \
    const float4 uB_ = u_lds[1][KL][gg][uq]; \
    pA.x += eA_*uA_.x; pA.y += eA_*uA_.y; pA.z += eA_*uA_.z; pA.w += eA_*uA_.w; \
    pB.x += eB_*uB_.x; pB.y += eB_*uB_.y; pB.z += eB_*uB_.z; pB.w += eB_*uB_.w; }

    // 4-stage reduce over gg-lanes only (uq-lane copies are identical,
    // so le is counted ONCE -> inv = 1/esum in SQUASH).
#define LERED_WRITE() { \
    leA += __shfl_xor(leA, 4);  leB += __shfl_xor(leB, 4); \
    leA += __shfl_xor(leA, 8);  leB += __shfl_xor(leB, 8); \
    leA += __shfl_xor(leA, 16); leB += __shfl_xor(leB, 16); \
    leA += __shfl_xor(leA, 32); leB += __shfl_xor(leB, 32); \
    if ((t & 63) == 0) { redB[0][wave] = leA; redB[1][wave] = leB; } }

    // ---- iteration 0: c is uniform 1/1152, no exp needed ----
    pA = uA0; pB = uB0;
    PADD(uA1, uB1) PADD(uA2, uB2) PADD(uA3, uB3)
    PADD(uA4, uB4) PADD(uA5, uB5)
    PADDL(0) PADDL(1) PADDL(2)
    PRED_WRITE()
    SQUASH(0, 0, 1)
    BUPD_ALL(1)            // b = 1 + u_hat . v0

    // ---- iteration 1 ----
    leA = 0.f; leB = 0.f;
    pA = make_float4(0.f, 0.f, 0.f, 0.f); pB = make_float4(0.f, 0.f, 0.f, 0.f);
    ACCE(0, uA0, uB0) ACCE(1, uA1, uB1) ACCE(2, uA2, uB2)
    ACCE(3, uA3, uB3) ACCE(4, uA4, uB4) ACCE(5, uA5, uB5)
    ACCEL(6, 0) ACCEL(7, 1) ACCEL(8, 2)
    LERED_WRITE()
    PRED_WRITE()
    SQUASH(1, 0, 1)
    BUPD_ALL(0)            // b += u_hat . v1

    // ---- iteration 2 (writes out; no trailing barrier) ----
    leA = 0.f; leB = 0.f;
    pA = make_float4(0.f, 0.f, 0.f, 0.f); pB = make_float4(0.f, 0.f, 0.f, 0.f);
    ACCE(0, uA0, uB0) ACCE(1, uA1, uB1) ACCE(2, uA2, uB2)
    ACCE(3, uA3, uB3) ACCE(4, uA4, uB4) ACCE(5, uA5, uB5)
    ACCEL(6, 0) ACCEL(7, 1) ACCEL(8, 2)
    LERED_WRITE()
    PRED_WRITE()
    SQUASH(1, 1, 0)
}

extern "C" void kernel_launch(void* const* d_in, const int* in_sizes, int n_in,
                              void* d_out, int out_size, void* d_ws, size_t ws_size,
                              hipStream_t stream) {
    const float* x = (const float*)d_in[0];   // (256, 1152, 8)
    const float* W = (const float*)d_in[1];   // (10, 1152, 8, 16)
    float* out = (float*)d_out;               // (256, 10, 16)
    capsule_routing_kernel<<<CAPS * (BATCH / 2), TPB, 0, stream>>>(x, W, out);
}

// Round 16
// 111.984 us; speedup vs baseline: 1.1271x; 1.0069x over previous
//
#include <hip/hip_runtime.h>
#include <math.h>

// Capsule dynamic routing, fully fused, 2-BATCH + u_hat SPLIT REG/LDS:
// one block of 512 threads per (c, batch-pair). B=256, C=10, N=1152,
// Din=8, U=16, 3 routing iterations.
//
// Round-16 = R15 (61us rocprof, clean; exp2f diet gave +18%) + partial
// din-MERGE for u_hat groups 0-3. Budget model: VALU ~19.5us, W stream
// 0.85 GB @ ~18 TB/s L2 ~= 47us, floor ~50us; the 61-50 gap is the 18
// serialized load-stall points in the UHC phase. Live-set peak is set by
// LATE groups (held 48 + in-flight 24 + misc ~48 = 120 measured), so
// merging EARLY groups k<=3 (peak 8k+48+48 <= 120) removes 4 stall
// points at the SAME register peak -> no regalloc change expected.
// Group 4 would hit exactly 128 -> left split. Groups 4-8 unchanged.
//  * expf -> exp2f(b*LOG2E); LERED 4-stage; no dead final barrier (R15).
//  * u_hat groups 0-5 in 12 NAMED float4 regs; groups 6-8 in LDS (48 KB,
//    same-thread write/read, no barrier); b logits in LDS; x from global;
//    iter 0 peeled; launch_bounds(512,2); c-major grid.

#define BATCH 256
#define CAPS  10
#define NIN   1152
#define DIN   8
#define UDIM  16
#define TPB   512
#define LOG2E 1.4426950408889634f

__global__ __launch_bounds__(TPB, 2) void capsule_routing_kernel(
    const float* __restrict__ x,   // (B, N, Din)
    const float* __restrict__ W,   // (C, N, Din, U)
    float* __restrict__ out)       // (B, C, U)
{
    const int gblk = blockIdx.x;      // c-major for L2 W-locality
    const int c    = gblk >> 7;       // 0..9
    const int bp   = gblk & 127;      // 0..127  (batch pair)
    const int b0   = bp << 1;
    const int t    = threadIdx.x;     // 0..511
    const int uq   = t & 3;           // u quarter: 0..3
    const int ub   = uq << 2;         // u base: 0,4,8,12
    const int gg   = t >> 2;          // 0..127 (n residue)
    const int wave = t >> 6;          // 0..7

    __shared__ float  b_s[2][NIN];        // routing logits (9.2 KB)
    __shared__ float  redB[2][8];         // per-wave exp-sum partials
    __shared__ float  ps[2][8][UDIM];     // per-wave partial s
    __shared__ float  v_s[2][UDIM];       // squashed output
    __shared__ float4 u_lds[2][3][128][4]; // u_hat groups 6-8 (48 KB)

    const float* Wc = W + (size_t)c * (NIN * DIN * UDIM);
    const float* xA = x + (size_t)b0 * (NIN * DIN);
    const float* xB = xA + (NIN * DIN);

    // u_hat groups 0-5 in 12 NAMED float4 registers (array form spills)
    float4 uA0,uA1,uA2,uA3,uA4,uA5;
    float4 uB0,uB1,uB2,uB3,uB4,uB5;

    // MERGED body (groups 0-3 only): all 12 loads (8 W + 4 x float4) in
    // flight together -> one stall point. Safe only while held u_hat is
    // small (8k + 48 + misc <= 128).
#define UHBODY_M(K, A_, D_) { \
    const int n_ = gg + 128 * (K); \
    const float4* wr_ = (const float4*)(Wc + n_ * (DIN * UDIM) + ub); \
    const float4 xa_ = ((const float4*)(xA + n_ * DIN))[0]; \
    const float4 xb_ = ((const float4*)(xA + n_ * DIN))[1]; \
    const float4 ya_ = ((const float4*)(xB + n_ * DIN))[0]; \
    const float4 yb_ = ((const float4*)(xB + n_ * DIN))[1]; \
    const float4 w0_ = wr_[0],  w1_ = wr_[4],  w2_ = wr_[8],  w3_ = wr_[12]; \
    const float4 w4_ = wr_[16], w5_ = wr_[20], w6_ = wr_[24], w7_ = wr_[28]; \
    A_.x = xa_.x*w0_.x + xa_.y*w1_.x + xa_.z*w2_.x + xa_.w*w3_.x \
         + xb_.x*w4_.x + xb_.y*w5_.x + xb_.z*w6_.x + xb_.w*w7_.x; \
    A_.y = xa_.x*w0_.y + xa_.y*w1_.y + xa_.z*w2_.y + xa_.w*w3_.y \
         + xb_.x*w4_.y + xb_.y*w5_.y + xb_.z*w6_.y + xb_.w*w7_.y; \
    A_.z = xa_.x*w0_.z + xa_.y*w1_.z + xa_.z*w2_.z + xa_.w*w3_.z \
         + xb_.x*w4_.z + xb_.y*w5_.z + xb_.z*w6_.z + xb_.w*w7_.z; \
    A_.w = xa_.x*w0_.w + xa_.y*w1_.w + xa_.z*w2_.w + xa_.w*w3_.w \
         + xb_.x*w4_.w + xb_.y*w5_.w + xb_.z*w6_.w + xb_.w*w7_.w; \
    D_.x = ya_.x*w0_.x + ya_.y*w1_.x + ya_.z*w2_.x + ya_.w*w3_.x \
         + yb_.x*w4_.x + yb_.y*w5_.x + yb_.z*w6_.x + yb_.w*w7_.x; \
    D_.y = ya_.x*w0_.y + ya_.y*w1_.y + ya_.z*w2_.y + ya_.w*w3_.y \
         + yb_.x*w4_.y + yb_.y*w5_.y + yb_.z*w6_.y + yb_.w*w7_.y; \
    D_.z = ya_.x*w0_.z + ya_.y*w1_.z + ya_.z*w2_.z + ya_.w*w3_.z \
         + yb_.x*w4_.z + yb_.y*w5_.z + yb_.z*w6_.z + yb_.w*w7_.z; \
    D_.w = ya_.x*w0_.w + ya_.y*w1_.w + ya_.z*w2_.w + ya_.w*w3_.w \
         + yb_.x*w4_.w + yb_.y*w5_.w + yb_.z*w6_.w + yb_.w*w7_.w; } \
    __builtin_amdgcn_sched_barrier(0);

    // SPLIT body (groups 4-8): din-halves separated (in-flight 6 float4) --
    // required once held u_hat is large (R6/R12's proven-clean form).
#define UHBODY(K, A_, D_) { \
    const int n_ = gg + 128 * (K); \
    const float4* wr_ = (const float4*)(Wc + n_ * (DIN * UDIM) + ub); \
    { /* din 0..3 */ \
        const float4 xa_ = ((const float4*)(xA + n_ * DIN))[0]; \
        const float4 ya_ = ((const float4*)(xB + n_ * DIN))[0]; \
        const float4 w0_ = wr_[0], w1_ = wr_[4], w2_ = wr_[8], w3_ = wr_[12]; \
        A_.x = xa_.x*w0_.x + xa_.y*w1_.x + xa_.z*w2_.x + xa_.w*w3_.x; \
        A_.y = xa_.x*w0_.y + xa_.y*w1_.y + xa_.z*w2_.y + xa_.w*w3_.y; \
        A_.z = xa_.x*w0_.z + xa_.y*w1_.z + xa_.z*w2_.z + xa_.w*w3_.z; \
        A_.w = xa_.x*w0_.w + xa_.y*w1_.w + xa_.z*w2_.w + xa_.w*w3_.w; \
        D_.x = ya_.x*w0_.x + ya_.y*w1_.x + ya_.z*w2_.x + ya_.w*w3_.x; \
        D_.y = ya_.x*w0_.y + ya_.y*w1_.y + ya_.z*w2_.y + ya_.w*w3_.y; \
        D_.z = ya_.x*w0_.z + ya_.y*w1_.z + ya_.z*w2_.z + ya_.w*w3_.z; \
        D_.w = ya_.x*w0_.w + ya_.y*w1_.w + ya_.z*w2_.w + ya_.w*w3_.w; \
    } \
    __builtin_amdgcn_sched_barrier(0); \
    { /* din 4..7 */ \
        const float4 xb_ = ((const float4*)(xA + n_ * DIN))[1]; \
        const float4 yb_ = ((const float4*)(xB + n_ * DIN))[1]; \
        const float4 w4_ = wr_[16], w5_ = wr_[20], w6_ = wr_[24], w7_ = wr_[28]; \
        A_.x += xb_.x*w4_.x + xb_.y*w5_.x + xb_.z*w6_.x + xb_.w*w7_.x; \
        A_.y += xb_.x*w4_.y + xb_.y*w5_.y + xb_.z*w6_.y + xb_.w*w7_.y; \
        A_.z += xb_.x*w4_.z + xb_.y*w5_.z + xb_.z*w6_.z + xb_.w*w7_.z; \
        A_.w += xb_.x*w4_.w + xb_.y*w5_.w + xb_.z*w6_.w + xb_.w*w7_.w; \
        D_.x += yb_.x*w4_.x + yb_.y*w5_.x + yb_.z*w6_.x + yb_.w*w7_.x; \
        D_.y += yb_.x*w4_.y + yb_.y*w5_.y + yb_.z*w6_.y + yb_.w*w7_.y; \
        D_.z += yb_.x*w4_.z + yb_.y*w5_.z + yb_.z*w6_.z + yb_.w*w7_.z; \
        D_.w += yb_.x*w4_.w + yb_.y*w5_.w + yb_.z*w6_.w + yb_.w*w7_.w; \
    } } \
    __builtin_amdgcn_sched_barrier(0);

    // groups 0-3: merged windows (held u_hat small); 4-5: split; -> regs
    UHBODY_M(0, uA0, uB0)
    UHBODY_M(1, uA1, uB1)
    UHBODY_M(2, uA2, uB2)
    UHBODY_M(3, uA3, uB3)
    UHBODY(4, uA4, uB4)
    UHBODY(5, uA5, uB5)
    // groups 6-8 -> LDS (same-thread write/read; no barrier needed)
    {
        float4 a_, d_;
        UHBODY(6, a_, d_)  u_lds[0][0][gg][uq] = a_; u_lds[1][0][gg][uq] = d_;
        UHBODY(7, a_, d_)  u_lds[0][1][gg][uq] = a_; u_lds[1][1][gg][uq] = d_;
        UHBODY(8, a_, d_)  u_lds[0][2][gg][uq] = a_; u_lds[1][2][gg][uq] = d_;
    }

    float4 pA, pB;
    float leA, leB;

    // ---- reduction helpers ----
#define PSTAGE(MK) { \
    pA.x += __shfl_xor(pA.x, MK); pA.y += __shfl_xor(pA.y, MK); \
    pA.z += __shfl_xor(pA.z, MK); pA.w += __shfl_xor(pA.w, MK); \
    pB.x += __shfl_xor(pB.x, MK); pB.y += __shfl_xor(pB.y, MK); \
    pB.z += __shfl_xor(pB.z, MK); pB.w += __shfl_xor(pB.w, MK); }

#define PRED_WRITE() { \
    PSTAGE(4) PSTAGE(8) PSTAGE(16) PSTAGE(32) \
    if ((t & 63) < 4) { \
        ps[0][wave][ub+0] = pA.x; ps[0][wave][ub+1] = pA.y; \
        ps[0][wave][ub+2] = pA.z; ps[0][wave][ub+3] = pA.w; \
        ps[1][wave][ub+0] = pB.x; ps[1][wave][ub+1] = pB.y; \
        ps[1][wave][ub+2] = pB.z; ps[1][wave][ub+3] = pB.w; \
    } }

    // squash: threads 0..31 (wave 0). bi = batch, u = component.
    // LASTB: emit the trailing barrier (skip on the final iteration).
#define SQUASH(USE_RED, WROUT, LASTB) { \
    __syncthreads(); \
    if (t < 32) { \
        const int bi_ = t >> 4, u_ = t & 15; \
        float inv_; \
        if (USE_RED) { \
            float es_ = 0.f; \
            es_ += redB[bi_][0]; es_ += redB[bi_][1]; es_ += redB[bi_][2]; es_ += redB[bi_][3]; \
            es_ += redB[bi_][4]; es_ += redB[bi_][5]; es_ += redB[bi_][6]; es_ += redB[bi_][7]; \
            inv_ = 1.0f / es_;               /* le counted once (4-stage) */ \
        } else { \
            inv_ = 1.0f / 1152.0f;           /* softmax(ones) is uniform */ \
        } \
        float s_ = 0.f; \
        s_ += ps[bi_][0][u_]; s_ += ps[bi_][1][u_]; s_ += ps[bi_][2][u_]; s_ += ps[bi_][3][u_]; \
        s_ += ps[bi_][4][u_]; s_ += ps[bi_][5][u_]; s_ += ps[bi_][6][u_]; s_ += ps[bi_][7][u_]; \
        s_ *= inv_; \
        float sq_ = s_ * s_; \
        sq_ += __shfl_xor(sq_, 1); sq_ += __shfl_xor(sq_, 2); \
        sq_ += __shfl_xor(sq_, 4); sq_ += __shfl_xor(sq_, 8); \
        const float sc_ = sq_ / ((1.0f + sq_) * sqrtf(sq_ + 1e-9f)); \
        const float v_ = sc_ * s_; \
        v_s[bi_][u_] = v_; \
        if (WROUT) out[((size_t)(b0 + bi_) * CAPS + c) * UDIM + u_] = v_; \
    } \
    if (LASTB) __syncthreads(); }

    // b update from register-held groups
#define BUP(K, UA, UB, INIT) { \
    float qa_ = UA.x*vA_.x + UA.y*vA_.y + UA.z*vA_.z + UA.w*vA_.w; \
    float qb_ = UB.x*vB_.x + UB.y*vB_.y + UB.z*vB_.z + UB.w*vB_.w; \
    qa_ += __shfl_xor(qa_, 1); qa_ += __shfl_xor(qa_, 2); \
    qb_ += __shfl_xor(qb_, 1); qb_ += __shfl_xor(qb_, 2); \
    if ((t & 3) == 0) { \
        const int n_ = gg + 128 * (K); \
        if (INIT) { b_s[0][n_] = 1.0f + qa_; b_s[1][n_] = 1.0f + qb_; } \
        else      { b_s[0][n_] += qa_;       b_s[1][n_] += qb_; } \
    } }

    // b update from LDS-held groups
#define BUPL(K, KL, INIT) { \
    const float4 uA_ = u_lds[0][KL][gg][uq]; \
    const float4 uB_ = u_lds[1][KL][gg][uq]; \
    float qa_ = uA_.x*vA_.x + uA_.y*vA_.y + uA_.z*vA_.z + uA_.w*vA_.w; \
    float qb_ = uB_.x*vB_.x + uB_.y*vB_.y + uB_.z*vB_.z + uB_.w*vB_.w; \
    qa_ += __shfl_xor(qa_, 1); qa_ += __shfl_xor(qa_, 2); \
    qb_ += __shfl_xor(qb_, 1); qb_ += __shfl_xor(qb_, 2); \
    if ((t & 3) == 0) { \
        const int n_ = gg + 128 * (K); \
        if (INIT) { b_s[0][n_] = 1.0f + qa_; b_s[1][n_] = 1.0f + qb_; } \
        else      { b_s[0][n_] += qa_;       b_s[1][n_] += qb_; } \
    } }

#define BUPD_ALL(INIT) { \
    const float4 vA_ = *(const float4*)(&v_s[0][ub]); \
    const float4 vB_ = *(const float4*)(&v_s[1][ub]); \
    BUP(0, uA0, uB0, INIT) BUP(1, uA1, uB1, INIT) \
    BUP(2, uA2, uB2, INIT) BUP(3, uA3, uB3, INIT) \
    BUP(4, uA4, uB4, INIT) BUP(5, uA5, uB5, INIT) \
    BUPL(6, 0, INIT) BUPL(7, 1, INIT) BUPL(8, 2, INIT) \
    __syncthreads(); }

#define PADD(UA, UB) { \
    pA.x += UA.x; pA.y += UA.y; pA.z += UA.z; pA.w += UA.w; \
    pB.x += UB.x; pB.y += UB.y; pB.z += UB.z; pB.w += UB.w; }

#define PADDL(KL) { \
    const float4 uA_ = u_lds[0][KL][gg][uq]; \
    const float4 uB_ = u_lds[1][KL][gg][uq]; \
    pA.x += uA_.x; pA.y += uA_.y; pA.z += uA_.z; pA.w += uA_.w; \
    pB.x += uB_.x; pB.y += uB_.y; pB.z += uB_.z; pB.w += uB_.w; }

    // fast exp: exp(b) = exp2(b * log2 e) -> v_mul + v_exp_f32 (~1 ulp).
#define ACCE(K, UA, UB) { \
    const float eA_ = exp2f(b_s[0][gg + 128*(K)] * LOG2E); \
    const float eB_ = exp2f(b_s[1][gg + 128*(K)] * LOG2E); \
    leA += eA_; leB += eB_; \
    pA.x += eA_*UA.x; pA.y += eA_*UA.y; pA.z += eA_*UA.z; pA.w += eA_*UA.w; \
    pB.x += eB_*UB.x; pB.y += eB_*UB.y; pB.z += eB_*UB.z; pB.w += eB_*UB.w; }

#define ACCEL(K, KL) { \
    const float eA_ = exp2f(b_s[0][gg + 128*(K)] * LOG2E); \
    const float eB_ = exp2f(b_s[1][gg + 128*(K)] * LOG2E); \
    leA += eA_; leB += eB_; \
    const float4 uA_ = u_lds[0][KL][gg][uq]; \
    const float4 uB_ = u_lds[1][KL][gg][uq]; \
    pA.x += eA_*uA_.x; pA.y += eA_*uA_.y; pA.z += eA_*uA_.z; pA.w += eA_*uA_.w; \
    pB.x += eB_*uB_.x; pB.y += eB_*uB_.y; pB.z += eB_*uB_.z; pB.w += eB_*uB_.w; }

    // 4-stage reduce over gg-lanes only (uq-lane copies are identical,
    // so le is counted ONCE -> inv = 1/esum in SQUASH).
#define LERED_WRITE() { \
    leA += __shfl_xor(leA, 4);  leB += __shfl_xor(leB, 4); \
    leA += __shfl_xor(leA, 8);  leB += __shfl_xor(leB, 8); \
    leA += __shfl_xor(leA, 16); leB += __shfl_xor(leB, 16); \
    leA += __shfl_xor(leA, 32); leB += __shfl_xor(leB, 32); \
    if ((t & 63) == 0) { redB[0][wave] = leA; redB[1][wave] = leB; } }

    // ---- iteration 0: c is uniform 1/1152, no exp needed ----
    pA = uA0; pB = uB0;
    PADD(uA1, uB1) PADD(uA2, uB2) PADD(uA3, uB3)
    PADD(uA4, uB4) PADD(uA5, uB5)
    PADDL(0) PADDL(1) PADDL(2)
    PRED_WRITE()
    SQUASH(0, 0, 1)
    BUPD_ALL(1)            // b = 1 + u_hat . v0

    // ---- iteration 1 ----
    leA = 0.f; leB = 0.f;
    pA = make_float4(0.f, 0.f, 0.f, 0.f); pB = make_float4(0.f, 0.f, 0.f, 0.f);
    ACCE(0, uA0, uB0) ACCE(1, uA1, uB1) ACCE(2, uA2, uB2)
    ACCE(3, uA3, uB3) ACCE(4, uA4, uB4) ACCE(5, uA5, uB5)
    ACCEL(6, 0) ACCEL(7, 1) ACCEL(8, 2)
    LERED_WRITE()
    PRED_WRITE()
    SQUASH(1, 0, 1)
    BUPD_ALL(0)            // b += u_hat . v1

    // ---- iteration 2 (writes out; no trailing barrier) ----
    leA = 0.f; leB = 0.f;
    pA = make_float4(0.f, 0.f, 0.f, 0.f); pB = make_float4(0.f, 0.f, 0.f, 0.f);
    ACCE(0, uA0, uB0) ACCE(1, uA1, uB1) ACCE(2, uA2, uB2)
    ACCE(3, uA3, uB3) ACCE(4, uA4, uB4) ACCE(5, uA5, uB5)
    ACCEL(6, 0) ACCEL(7, 1) ACCEL(8, 2)
    LERED_WRITE()
    PRED_WRITE()
    SQUASH(1, 1, 0)
}

extern "C" void kernel_launch(void* const* d_in, const int* in_sizes, int n_in,
                              void* d_out, int out_size, void* d_ws, size_t ws_size,
                              hipStream_t stream) {
    const float* x = (const float*)d_in[0];   // (256, 1152, 8)
    const float* W = (const float*)d_in[1];   // (10, 1152, 8, 16)
    float* out = (float*)d_out;               // (256, 10, 16)
    capsule_routing_kernel<<<CAPS * (BATCH / 2), TPB, 0, stream>>>(x, W, out);
}